// Round 1
// baseline (2386.140 us; speedup 1.0000x reference)
//
#include <hip/hip_runtime.h>
#include <cstdint>
#include <cstddef>

// Problem constants (match reference)
constexpr int Nn = 50000;
constexpr int Ne = 500000;
constexpr int Gg = 64;
constexpr int DIN = 128, ED = 32, H1 = 256, H2 = 128, HD = 64, NOUT = 8;

// ---------------- CSR build ----------------
__global__ void count_deg_kernel(const int* __restrict__ dst, int* __restrict__ deg) {
    int e = blockIdx.x * 256 + threadIdx.x;
    if (e < Ne) atomicAdd(&deg[dst[e]], 1);
}

__global__ __launch_bounds__(1024) void scan_kernel(const int* __restrict__ deg,
                                                    int* __restrict__ row_start) {
    __shared__ int part[1024];
    int t = threadIdx.x;
    const int chunk = (Nn + 1023) / 1024;
    int lo = t * chunk;
    int hi = min(lo + chunk, Nn);
    int s = 0;
    for (int i = lo; i < hi; i++) s += deg[i];
    part[t] = s;
    __syncthreads();
    for (int off = 1; off < 1024; off <<= 1) {
        int add = (t >= off) ? part[t - off] : 0;
        __syncthreads();
        part[t] += add;
        __syncthreads();
    }
    int base = (t == 0) ? 0 : part[t - 1];
    for (int i = lo; i < hi; i++) { row_start[i] = base; base += deg[i]; }
    if (t == 0) row_start[Nn] = Ne;
}

__global__ void scatter_kernel(const int* __restrict__ dst, const int* __restrict__ row_start,
                               int* __restrict__ cursor, int* __restrict__ perm) {
    int e = blockIdx.x * 256 + threadIdx.x;
    if (e < Ne) {
        int d = dst[e];
        int p = atomicAdd(&cursor[d], 1);
        perm[row_start[d] + p] = e;
    }
}

// loop_attr[i] = mean of incoming edge_attr rows (self-loop feature, fill_value='mean')
__global__ void loop_attr_kernel(const float* __restrict__ eattr, const int* __restrict__ row_start,
                                 const int* __restrict__ perm, float* __restrict__ loop_attr) {
    int tid = blockIdx.x * 256 + threadIdx.x;
    if (tid >= Nn * ED) return;
    int i = tid / ED, c = tid % ED;
    int r0 = row_start[i], r1 = row_start[i + 1];
    float s = 0.f;
    for (int j = r0; j < r1; j++) s += eattr[(size_t)perm[j] * ED + c];
    loop_attr[tid] = s / fmaxf((float)(r1 - r0), 1.0f);
}

// ---------------- fp32 GEMM: C[M,Nc] = A[M,K] @ W[K,Nc] + bias ----------------
__global__ __launch_bounds__(256) void gemm_bias_kernel(const float* __restrict__ A,
                                                        const float* __restrict__ W,
                                                        const float* __restrict__ bias,
                                                        float* __restrict__ C,
                                                        int M, int K, int Ncols) {
    __shared__ float As[16][68];  // [k][m], padded
    __shared__ float Bs[16][68];  // [k][n], padded (row stride 272B = 16B aligned)
    const int m0 = blockIdx.y * 64, n0 = blockIdx.x * 64;
    const int tid = threadIdx.x;
    const int tx = tid & 15, ty = tid >> 4;
    float acc[4][4] = {};
    const int ar = tid >> 2, ac4 = (tid & 3) << 2;
    const int br = tid >> 4, bc4 = (tid & 15) << 2;
    for (int k0 = 0; k0 < K; k0 += 16) {
        float4 av = make_float4(0.f, 0.f, 0.f, 0.f);
        if (m0 + ar < M) av = *(const float4*)(A + (size_t)(m0 + ar) * K + k0 + ac4);
        As[ac4 + 0][ar] = av.x; As[ac4 + 1][ar] = av.y;
        As[ac4 + 2][ar] = av.z; As[ac4 + 3][ar] = av.w;
        float4 bv = *(const float4*)(W + (size_t)(k0 + br) * Ncols + n0 + bc4);
        *(float4*)&Bs[br][bc4] = bv;
        __syncthreads();
#pragma unroll
        for (int k = 0; k < 16; k++) {
            float a[4], b[4];
#pragma unroll
            for (int i = 0; i < 4; i++) a[i] = As[k][ty * 4 + i];
#pragma unroll
            for (int j = 0; j < 4; j++) b[j] = Bs[k][tx * 4 + j];
#pragma unroll
            for (int i = 0; i < 4; i++)
#pragma unroll
                for (int j = 0; j < 4; j++) acc[i][j] = fmaf(a[i], b[j], acc[i][j]);
        }
        __syncthreads();
    }
#pragma unroll
    for (int i = 0; i < 4; i++) {
        int m = m0 + ty * 4 + i;
        if (m < M) {
            float4 o;
            o.x = acc[i][0] + bias[n0 + tx * 4 + 0];
            o.y = acc[i][1] + bias[n0 + tx * 4 + 1];
            o.z = acc[i][2] + bias[n0 + tx * 4 + 2];
            o.w = acc[i][3] + bias[n0 + tx * 4 + 3];
            *(float4*)(C + (size_t)m * Ncols + n0 + tx * 4) = o;
        }
    }
}

// ---------------- edge scores: s = att . leakyrelu(xl[src]+xr[dst]+eattr@We, 0.2) ----------------
template <int C>
__global__ __launch_bounds__(256) void edge_score_kernel(
    const int* __restrict__ src, const int* __restrict__ dst,
    const float* __restrict__ eattr,
    const float* __restrict__ xl, const float* __restrict__ xr,
    const float* __restrict__ We, const float* __restrict__ att,
    float* __restrict__ out, int count, int selfloop) {
    constexpr int VP = C / 64;
    __shared__ float sWe[ED * C];
    __shared__ float sAtt[C];
    for (int i = threadIdx.x; i < ED * C; i += 256) sWe[i] = We[i];
    for (int i = threadIdx.x; i < C; i += 256) sAtt[i] = att[i];
    __syncthreads();
    const int wave = threadIdx.x >> 6, lane = threadIdx.x & 63;
    const int stride = gridDim.x * 4 * 4;  // waves * 4 edges each
    for (int base = (blockIdx.x * 4 + wave) * 4; base < count; base += stride) {
        float ea[4];
        float acc[4][VP];
#pragma unroll
        for (int q = 0; q < 4; q++) {
            int e = min(base + q, count - 1);
            int s = selfloop ? e : src[e];
            int d = selfloop ? e : dst[e];
            ea[q] = (lane < ED) ? eattr[(size_t)e * ED + lane] : 0.f;
            const float* xls = xl + (size_t)s * C + lane * VP;
            const float* xrd = xr + (size_t)d * C + lane * VP;
            if constexpr (VP == 4) {
                float4 u = *(const float4*)xls;
                float4 v = *(const float4*)xrd;
                acc[q][0] = u.x + v.x; acc[q][1] = u.y + v.y;
                acc[q][2] = u.z + v.z; acc[q][3] = u.w + v.w;
            } else {
                float2 u = *(const float2*)xls;
                float2 v = *(const float2*)xrd;
                acc[q][0] = u.x + v.x; acc[q][1] = u.y + v.y;
            }
        }
#pragma unroll
        for (int k = 0; k < ED; k++) {
            float wv[VP];
            if constexpr (VP == 4) {
                float4 t = *(const float4*)&sWe[k * C + lane * 4];
                wv[0] = t.x; wv[1] = t.y; wv[2] = t.z; wv[3] = t.w;
            } else {
                float2 t = *(const float2*)&sWe[k * C + lane * 2];
                wv[0] = t.x; wv[1] = t.y;
            }
#pragma unroll
            for (int q = 0; q < 4; q++) {
                float w = __shfl(ea[q], k);
#pragma unroll
                for (int j = 0; j < VP; j++) acc[q][j] = fmaf(w, wv[j], acc[q][j]);
            }
        }
        float attv[VP];
#pragma unroll
        for (int j = 0; j < VP; j++) attv[j] = sAtt[lane * VP + j];
#pragma unroll
        for (int q = 0; q < 4; q++) {
            float p = 0.f;
#pragma unroll
            for (int j = 0; j < VP; j++) {
                float v = acc[q][j];
                v = v > 0.f ? v : 0.2f * v;
                p = fmaf(v, attv[j], p);
            }
#pragma unroll
            for (int off = 32; off >= 1; off >>= 1) p += __shfl_xor(p, off);
            if (lane == 0 && base + q < count) out[base + q] = p;
        }
    }
}

// ---------------- softmax + aggregate per node (wave per node) ----------------
template <int C>
__global__ __launch_bounds__(256) void aggregate_kernel(
    const int* __restrict__ row_start, const int* __restrict__ perm,
    const int* __restrict__ src,
    const float* __restrict__ scores, const float* __restrict__ sscore,
    const float* __restrict__ xl, const float* __restrict__ bias,
    float* __restrict__ xout) {
    constexpr int VP = C / 64;
    const int wave = threadIdx.x >> 6, lane = threadIdx.x & 63;
    int i = blockIdx.x * 4 + wave;
    if (i >= Nn) return;
    int r0 = row_start[i], r1 = row_start[i + 1];
    int d = r1 - r0;
    float ss = sscore[i];
    // max over incoming + self
    float m = ss;
    for (int j = r0 + lane; j < r1; j += 64) m = fmaxf(m, scores[perm[j]]);
#pragma unroll
    for (int off = 32; off >= 1; off >>= 1) m = fmaxf(m, __shfl_xor(m, off));
    // sum of exp
    float myexp0 = 0.f;
    if (lane < d) myexp0 = expf(scores[perm[r0 + lane]] - m);
    float dsum = (lane == 0) ? expf(ss - m) : 0.f;
    dsum += myexp0;
    for (int j = r0 + 64 + lane; j < r1; j += 64) dsum += expf(scores[perm[j]] - m);
#pragma unroll
    for (int off = 32; off >= 1; off >>= 1) dsum += __shfl_xor(dsum, off);
    float inv = 1.0f / dsum;
    float myalpha = myexp0 * inv;  // alpha for edge r0+lane (lane<d, lane<64)

    float acc[VP];
    {
        float aself = expf(ss - m) * inv;
        const float* xi = xl + (size_t)i * C + lane * VP;
        if constexpr (VP == 4) {
            float4 v = *(const float4*)xi;
            acc[0] = aself * v.x; acc[1] = aself * v.y;
            acc[2] = aself * v.z; acc[3] = aself * v.w;
        } else {
            float2 v = *(const float2*)xi;
            acc[0] = aself * v.x; acc[1] = aself * v.y;
        }
    }
    for (int j = 0; j < d; j++) {
        int e = perm[r0 + j];
        float a = (j < 64) ? __shfl(myalpha, j) : expf(scores[e] - m) * inv;
        int s = src[e];
        const float* xs = xl + (size_t)s * C + lane * VP;
        if constexpr (VP == 4) {
            float4 v = *(const float4*)xs;
            acc[0] = fmaf(a, v.x, acc[0]); acc[1] = fmaf(a, v.y, acc[1]);
            acc[2] = fmaf(a, v.z, acc[2]); acc[3] = fmaf(a, v.w, acc[3]);
        } else {
            float2 v = *(const float2*)xs;
            acc[0] = fmaf(a, v.x, acc[0]); acc[1] = fmaf(a, v.y, acc[1]);
        }
    }
    float* xo = xout + (size_t)i * C + lane * VP;
#pragma unroll
    for (int j = 0; j < VP; j++) {
        float v = acc[j] + bias[lane * VP + j];
        xo[j] = fmaxf(v, 0.f);  // relu
    }
}

// ---------------- global mean pool ----------------
__global__ void pool_kernel(const float* __restrict__ x2, const int* __restrict__ batch,
                            float* __restrict__ pooled, float* __restrict__ cnt) {
    int tid = blockIdx.x * 256 + threadIdx.x;
    if (tid >= Nn * (H2 / 4)) return;
    int i = tid >> 5, q = tid & 31;
    int g = batch[i];
    float4 v = *(const float4*)(x2 + (size_t)i * H2 + q * 4);
    atomicAdd(&pooled[g * H2 + q * 4 + 0], v.x);
    atomicAdd(&pooled[g * H2 + q * 4 + 1], v.y);
    atomicAdd(&pooled[g * H2 + q * 4 + 2], v.z);
    atomicAdd(&pooled[g * H2 + q * 4 + 3], v.w);
    if (q == 0) atomicAdd(&cnt[g], 1.0f);
}

// ---------------- MLP head: x@Wd1+bd1 -> BN -> leaky(0.1) -> @Wd2+bd2 ----------------
__global__ __launch_bounds__(64) void head_kernel(
    const float* __restrict__ pooled, const float* __restrict__ cnt,
    const float* __restrict__ Wd1, const float* __restrict__ bd1,
    const float* __restrict__ gamma, const float* __restrict__ beta,
    const float* __restrict__ mean, const float* __restrict__ var,
    const float* __restrict__ Wd2, const float* __restrict__ bd2,
    float* __restrict__ out) {
    __shared__ float xm[H2];
    __shared__ float h[HD];
    int g = blockIdx.x, t = threadIdx.x;
    float c = fmaxf(cnt[g], 1.0f);
    for (int i = t; i < H2; i += 64) xm[i] = pooled[g * H2 + i] / c;
    __syncthreads();
    float a = bd1[t];
    for (int k = 0; k < H2; k++) a = fmaf(xm[k], Wd1[k * HD + t], a);
    a = (a - mean[t]) / sqrtf(var[t] + 1e-5f) * gamma[t] + beta[t];
    a = a > 0.f ? a : 0.1f * a;
    h[t] = a;
    __syncthreads();
    if (t < NOUT) {
        float o = bd2[t];
        for (int k = 0; k < HD; k++) o = fmaf(h[k], Wd2[k * NOUT + t], o);
        out[g * NOUT + t] = o;
    }
}

extern "C" void kernel_launch(void* const* d_in, const int* in_sizes, int n_in,
                              void* d_out, int out_size, void* d_ws, size_t ws_size,
                              hipStream_t stream) {
    const float* node_attr = (const float*)d_in[0];
    const float* edge_attr = (const float*)d_in[1];
    const int* edge_src = (const int*)d_in[2];
    const int* edge_dst = (const int*)d_in[3];
    const int* batch = (const int*)d_in[4];
    const float* Wl1 = (const float*)d_in[5];  const float* bl1 = (const float*)d_in[6];
    const float* Wr1 = (const float*)d_in[7];  const float* br1 = (const float*)d_in[8];
    const float* We1 = (const float*)d_in[9];  const float* att1 = (const float*)d_in[10];
    const float* b1 = (const float*)d_in[11];
    const float* Wl2 = (const float*)d_in[12]; const float* bl2 = (const float*)d_in[13];
    const float* Wr2 = (const float*)d_in[14]; const float* br2 = (const float*)d_in[15];
    const float* We2 = (const float*)d_in[16]; const float* att2 = (const float*)d_in[17];
    const float* b2 = (const float*)d_in[18];
    const float* Wd1 = (const float*)d_in[19]; const float* bd1 = (const float*)d_in[20];
    const float* bn_gamma = (const float*)d_in[21]; const float* bn_beta = (const float*)d_in[22];
    const float* bn_mean = (const float*)d_in[23];  const float* bn_var = (const float*)d_in[24];
    const float* Wd2 = (const float*)d_in[25]; const float* bd2 = (const float*)d_in[26];
    float* out = (float*)d_out;

    char* ws = (char*)d_ws;
    size_t off = 0;
    auto alloc = [&](size_t bytes) -> char* {
        char* p = ws + off;
        off = (off + bytes + 255) & ~(size_t)255;
        return p;
    };
    int* deg        = (int*)alloc((size_t)Nn * 4);
    int* row_start  = (int*)alloc((size_t)(Nn + 1) * 4);
    int* cursor     = (int*)alloc((size_t)Nn * 4);
    int* perm       = (int*)alloc((size_t)Ne * 4);
    float* loop_attr = (float*)alloc((size_t)Nn * ED * 4);
    float* scores   = (float*)alloc((size_t)Ne * 4);
    float* sscore   = (float*)alloc((size_t)Nn * 4);
    float* pooled   = (float*)alloc((size_t)Gg * H2 * 4);
    float* cnt      = (float*)alloc((size_t)Gg * 4);
    float* xlb      = (float*)alloc((size_t)Nn * H1 * 4);
    float* xrb      = (float*)alloc((size_t)Nn * H1 * 4);
    float* x1       = (float*)alloc((size_t)Nn * H1 * 4);

    hipMemsetAsync(deg, 0, (size_t)Nn * 4, stream);
    hipMemsetAsync(cursor, 0, (size_t)Nn * 4, stream);
    hipMemsetAsync(pooled, 0, (size_t)Gg * H2 * 4, stream);
    hipMemsetAsync(cnt, 0, (size_t)Gg * 4, stream);

    count_deg_kernel<<<(Ne + 255) / 256, 256, 0, stream>>>(edge_dst, deg);
    scan_kernel<<<1, 1024, 0, stream>>>(deg, row_start);
    scatter_kernel<<<(Ne + 255) / 256, 256, 0, stream>>>(edge_dst, row_start, cursor, perm);
    loop_attr_kernel<<<(Nn * ED + 255) / 256, 256, 0, stream>>>(edge_attr, row_start, perm, loop_attr);

    // ---- layer 1 ----
    gemm_bias_kernel<<<dim3(H1 / 64, (Nn + 63) / 64), 256, 0, stream>>>(node_attr, Wl1, bl1, xlb, Nn, DIN, H1);
    gemm_bias_kernel<<<dim3(H1 / 64, (Nn + 63) / 64), 256, 0, stream>>>(node_attr, Wr1, br1, xrb, Nn, DIN, H1);
    edge_score_kernel<H1><<<1024, 256, 0, stream>>>(edge_src, edge_dst, edge_attr, xlb, xrb, We1, att1, scores, Ne, 0);
    edge_score_kernel<H1><<<256, 256, 0, stream>>>(nullptr, nullptr, loop_attr, xlb, xrb, We1, att1, sscore, Nn, 1);
    aggregate_kernel<H1><<<Nn / 4, 256, 0, stream>>>(row_start, perm, edge_src, scores, sscore, xlb, b1, x1);

    // ---- layer 2 ----
    gemm_bias_kernel<<<dim3(H2 / 64, (Nn + 63) / 64), 256, 0, stream>>>(x1, Wl2, bl2, xlb, Nn, H1, H2);
    gemm_bias_kernel<<<dim3(H2 / 64, (Nn + 63) / 64), 256, 0, stream>>>(x1, Wr2, br2, xrb, Nn, H1, H2);
    edge_score_kernel<H2><<<1024, 256, 0, stream>>>(edge_src, edge_dst, edge_attr, xlb, xrb, We2, att2, scores, Ne, 0);
    edge_score_kernel<H2><<<256, 256, 0, stream>>>(nullptr, nullptr, loop_attr, xlb, xrb, We2, att2, sscore, Nn, 1);
    float* x2 = x1;  // reuse: x1 no longer needed once xl2/xr2 are built
    aggregate_kernel<H2><<<Nn / 4, 256, 0, stream>>>(row_start, perm, edge_src, scores, sscore, xlb, b2, x2);

    // ---- pool + head ----
    pool_kernel<<<(Nn * (H2 / 4) + 255) / 256, 256, 0, stream>>>(x2, batch, pooled, cnt);
    head_kernel<<<Gg, 64, 0, stream>>>(pooled, cnt, Wd1, bd1, bn_gamma, bn_beta,
                                       bn_mean, bn_var, Wd2, bd2, out);
}

// Round 2
// 2262.441 us; speedup vs baseline: 1.0547x; 1.0547x over previous
//
#include <hip/hip_runtime.h>
#include <cstdint>
#include <cstddef>

// Problem constants (match reference)
constexpr int Nn = 50000;
constexpr int Ne = 500000;
constexpr int Gg = 64;
constexpr int DIN = 128, ED = 32, H1 = 256, H2 = 128, HD = 64, NOUT = 8;

// ---------------- CSR build ----------------
__global__ void count_deg_kernel(const int* __restrict__ dst, int* __restrict__ deg) {
    int e = blockIdx.x * 256 + threadIdx.x;
    if (e < Ne) atomicAdd(&deg[dst[e]], 1);
}

__global__ __launch_bounds__(1024) void scan_kernel(const int* __restrict__ deg,
                                                    int* __restrict__ row_start) {
    __shared__ int part[1024];
    int t = threadIdx.x;
    const int chunk = (Nn + 1023) / 1024;
    int lo = t * chunk;
    int hi = min(lo + chunk, Nn);
    int s = 0;
    for (int i = lo; i < hi; i++) s += deg[i];
    part[t] = s;
    __syncthreads();
    for (int off = 1; off < 1024; off <<= 1) {
        int add = (t >= off) ? part[t - off] : 0;
        __syncthreads();
        part[t] += add;
        __syncthreads();
    }
    int base = (t == 0) ? 0 : part[t - 1];
    for (int i = lo; i < hi; i++) { row_start[i] = base; base += deg[i]; }
    if (t == 0) row_start[Nn] = Ne;
}

__global__ void scatter_kernel(const int* __restrict__ dst, const int* __restrict__ row_start,
                               int* __restrict__ cursor, int* __restrict__ perm) {
    int e = blockIdx.x * 256 + threadIdx.x;
    if (e < Ne) {
        int d = dst[e];
        int p = atomicAdd(&cursor[d], 1);
        perm[row_start[d] + p] = e;
    }
}

// ---------------- fp32 GEMM: C[M,Nc] = A[M,K] @ W[K,Nc] + bias (z=0/1 -> two weight sets) ----
__global__ __launch_bounds__(256) void gemm_bias2_kernel(const float* __restrict__ A,
                                                         const float* __restrict__ W0,
                                                         const float* __restrict__ bias0,
                                                         float* __restrict__ C0,
                                                         const float* __restrict__ W1,
                                                         const float* __restrict__ bias1,
                                                         float* __restrict__ C1,
                                                         int M, int K, int Ncols) {
    const float* W = blockIdx.z ? W1 : W0;
    const float* bias = blockIdx.z ? bias1 : bias0;
    float* C = blockIdx.z ? C1 : C0;
    __shared__ float As[16][68];  // [k][m], padded
    __shared__ float Bs[16][68];  // [k][n], padded
    const int m0 = blockIdx.y * 64, n0 = blockIdx.x * 64;
    const int tid = threadIdx.x;
    const int tx = tid & 15, ty = tid >> 4;
    float acc[4][4] = {};
    const int ar = tid >> 2, ac4 = (tid & 3) << 2;
    const int br = tid >> 4, bc4 = (tid & 15) << 2;
    for (int k0 = 0; k0 < K; k0 += 16) {
        float4 av = make_float4(0.f, 0.f, 0.f, 0.f);
        if (m0 + ar < M) av = *(const float4*)(A + (size_t)(m0 + ar) * K + k0 + ac4);
        As[ac4 + 0][ar] = av.x; As[ac4 + 1][ar] = av.y;
        As[ac4 + 2][ar] = av.z; As[ac4 + 3][ar] = av.w;
        float4 bv = *(const float4*)(W + (size_t)(k0 + br) * Ncols + n0 + bc4);
        *(float4*)&Bs[br][bc4] = bv;
        __syncthreads();
#pragma unroll
        for (int k = 0; k < 16; k++) {
            float a[4], b[4];
#pragma unroll
            for (int i = 0; i < 4; i++) a[i] = As[k][ty * 4 + i];
#pragma unroll
            for (int j = 0; j < 4; j++) b[j] = Bs[k][tx * 4 + j];
#pragma unroll
            for (int i = 0; i < 4; i++)
#pragma unroll
                for (int j = 0; j < 4; j++) acc[i][j] = fmaf(a[i], b[j], acc[i][j]);
        }
        __syncthreads();
    }
#pragma unroll
    for (int i = 0; i < 4; i++) {
        int m = m0 + ty * 4 + i;
        if (m < M) {
            float4 o;
            o.x = acc[i][0] + bias[n0 + tx * 4 + 0];
            o.y = acc[i][1] + bias[n0 + tx * 4 + 1];
            o.z = acc[i][2] + bias[n0 + tx * 4 + 2];
            o.w = acc[i][3] + bias[n0 + tx * 4 + 3];
            *(float4*)(C + (size_t)m * Ncols + n0 + tx * 4) = o;
        }
    }
}

// ---------------- fused GATv2 layer: score + online softmax + aggregate + self-loop ---------
// One wave per node. out[i] = relu( (sum_e alpha_e * xl[src_e] + alpha_self * xl[i]) + bias )
template <int C>
__global__ __launch_bounds__(256) void fused_gat_kernel(
    const int* __restrict__ row_start, const int* __restrict__ perm,
    const int* __restrict__ srcArr,
    const float* __restrict__ eattr,
    const float* __restrict__ xl, const float* __restrict__ xr,
    const float* __restrict__ We, const float* __restrict__ att,
    const float* __restrict__ bias, float* __restrict__ xout) {
    constexpr int VP = C / 64;
    __shared__ float sWe[ED * C];
    __shared__ float sAtt[C];
    for (int t = threadIdx.x; t < ED * C; t += 256) sWe[t] = We[t];
    for (int t = threadIdx.x; t < C; t += 256) sAtt[t] = att[t];
    __syncthreads();

    const int wave = threadIdx.x >> 6, lane = threadIdx.x & 63;
    const int i = blockIdx.x * 4 + wave;
    if (i >= Nn) return;

    const int r0 = row_start[i], r1 = row_start[i + 1];

    float xli[VP], xri[VP], attv[VP], biasv[VP];
    {
        const float* pl = xl + (size_t)i * C + lane * VP;
        const float* pr = xr + (size_t)i * C + lane * VP;
        if constexpr (VP == 4) {
            float4 a = *(const float4*)pl;
            float4 b = *(const float4*)pr;
            xli[0] = a.x; xli[1] = a.y; xli[2] = a.z; xli[3] = a.w;
            xri[0] = b.x; xri[1] = b.y; xri[2] = b.z; xri[3] = b.w;
        } else {
            float2 a = *(const float2*)pl;
            float2 b = *(const float2*)pr;
            xli[0] = a.x; xli[1] = a.y;
            xri[0] = b.x; xri[1] = b.y;
        }
#pragma unroll
        for (int j = 0; j < VP; j++) {
            attv[j] = sAtt[lane * VP + j];
            biasv[j] = bias[lane * VP + j];
        }
    }

    // score of one neighbor given its ea (lanes 0..31 hold eattr cols) and base = xs + xri
    auto score_of = [&](float ea, const float* base) -> float {
        float z0[VP], z1[VP];
#pragma unroll
        for (int j = 0; j < VP; j++) { z0[j] = base[j]; z1[j] = 0.f; }
#pragma unroll
        for (int k = 0; k < ED; k += 2) {
            float w0 = __shfl(ea, k);
            float w1 = __shfl(ea, k + 1);
            const float* r0p = &sWe[k * C + lane * VP];
            const float* r1p = &sWe[(k + 1) * C + lane * VP];
#pragma unroll
            for (int j = 0; j < VP; j++) z0[j] = fmaf(w0, r0p[j], z0[j]);
#pragma unroll
            for (int j = 0; j < VP; j++) z1[j] = fmaf(w1, r1p[j], z1[j]);
        }
        float p = 0.f;
#pragma unroll
        for (int j = 0; j < VP; j++) {
            float v = z0[j] + z1[j];
            v = v > 0.f ? v : 0.2f * v;
            p = fmaf(v, attv[j], p);
        }
#pragma unroll
        for (int off = 32; off >= 1; off >>= 1) p += __shfl_xor(p, off);
        return p;
    };

    float m = -INFINITY, l = 0.f;
    float acc[VP];
#pragma unroll
    for (int j = 0; j < VP; j++) acc[j] = 0.f;
    float ea_sum = 0.f;

    // 1-deep prefetch over incoming edges
    float ea_n = 0.f, xs_n[VP];
    auto load_edge = [&](int j) {
        int e = perm[j];
        int s = srcArr[e];
        ea_n = (lane < ED) ? eattr[(size_t)e * ED + lane] : 0.f;
        const float* p = xl + (size_t)s * C + lane * VP;
        if constexpr (VP == 4) {
            float4 v = *(const float4*)p;
            xs_n[0] = v.x; xs_n[1] = v.y; xs_n[2] = v.z; xs_n[3] = v.w;
        } else {
            float2 v = *(const float2*)p;
            xs_n[0] = v.x; xs_n[1] = v.y;
        }
    };
    if (r0 < r1) load_edge(r0);

    for (int j = r0; j < r1; j++) {
        float ea = ea_n;
        float xs[VP];
#pragma unroll
        for (int q = 0; q < VP; q++) xs[q] = xs_n[q];
        if (j + 1 < r1) load_edge(j + 1);

        ea_sum += ea;
        float base[VP];
#pragma unroll
        for (int q = 0; q < VP; q++) base[q] = xs[q] + xri[q];
        float sc = score_of(ea, base);

        float mnew = fmaxf(m, sc);
        float scale = __expf(m - mnew);   // m=-inf first iter -> 0
        float w = __expf(sc - mnew);
        l = fmaf(l, scale, w);
#pragma unroll
        for (int q = 0; q < VP; q++) acc[q] = fmaf(acc[q], scale, w * xs[q]);
        m = mnew;
    }

    // self-loop: ea = mean of incoming eattr (0 if no edges), x contribution = xl[i]
    {
        float d = (float)(r1 - r0);
        float la = ea_sum / fmaxf(d, 1.0f);
        float base[VP];
#pragma unroll
        for (int q = 0; q < VP; q++) base[q] = xli[q] + xri[q];
        float sc = score_of(la, base);
        float mnew = fmaxf(m, sc);
        float scale = __expf(m - mnew);
        float w = __expf(sc - mnew);
        l = fmaf(l, scale, w);
#pragma unroll
        for (int q = 0; q < VP; q++) acc[q] = fmaf(acc[q], scale, w * xli[q]);
    }

    float invl = 1.0f / l;
    float* xo = xout + (size_t)i * C + lane * VP;
    if constexpr (VP == 4) {
        float4 o;
        o.x = fmaxf(fmaf(acc[0], invl, biasv[0]), 0.f);
        o.y = fmaxf(fmaf(acc[1], invl, biasv[1]), 0.f);
        o.z = fmaxf(fmaf(acc[2], invl, biasv[2]), 0.f);
        o.w = fmaxf(fmaf(acc[3], invl, biasv[3]), 0.f);
        *(float4*)xo = o;
    } else {
        float2 o;
        o.x = fmaxf(fmaf(acc[0], invl, biasv[0]), 0.f);
        o.y = fmaxf(fmaf(acc[1], invl, biasv[1]), 0.f);
        *(float2*)xo = o;
    }
}

// ---------------- global mean pool ----------------
__global__ void pool_kernel(const float* __restrict__ x2, const int* __restrict__ batch,
                            float* __restrict__ pooled, float* __restrict__ cnt) {
    int tid = blockIdx.x * 256 + threadIdx.x;
    if (tid >= Nn * (H2 / 4)) return;
    int i = tid >> 5, q = tid & 31;
    int g = batch[i];
    float4 v = *(const float4*)(x2 + (size_t)i * H2 + q * 4);
    atomicAdd(&pooled[g * H2 + q * 4 + 0], v.x);
    atomicAdd(&pooled[g * H2 + q * 4 + 1], v.y);
    atomicAdd(&pooled[g * H2 + q * 4 + 2], v.z);
    atomicAdd(&pooled[g * H2 + q * 4 + 3], v.w);
    if (q == 0) atomicAdd(&cnt[g], 1.0f);
}

// ---------------- MLP head ----------------
__global__ __launch_bounds__(64) void head_kernel(
    const float* __restrict__ pooled, const float* __restrict__ cnt,
    const float* __restrict__ Wd1, const float* __restrict__ bd1,
    const float* __restrict__ gamma, const float* __restrict__ beta,
    const float* __restrict__ mean, const float* __restrict__ var,
    const float* __restrict__ Wd2, const float* __restrict__ bd2,
    float* __restrict__ out) {
    __shared__ float xm[H2];
    __shared__ float h[HD];
    int g = blockIdx.x, t = threadIdx.x;
    float c = fmaxf(cnt[g], 1.0f);
    for (int i = t; i < H2; i += 64) xm[i] = pooled[g * H2 + i] / c;
    __syncthreads();
    float a = bd1[t];
    for (int k = 0; k < H2; k++) a = fmaf(xm[k], Wd1[k * HD + t], a);
    a = (a - mean[t]) / sqrtf(var[t] + 1e-5f) * gamma[t] + beta[t];
    a = a > 0.f ? a : 0.1f * a;
    h[t] = a;
    __syncthreads();
    if (t < NOUT) {
        float o = bd2[t];
        for (int k = 0; k < HD; k++) o = fmaf(h[k], Wd2[k * NOUT + t], o);
        out[g * NOUT + t] = o;
    }
}

extern "C" void kernel_launch(void* const* d_in, const int* in_sizes, int n_in,
                              void* d_out, int out_size, void* d_ws, size_t ws_size,
                              hipStream_t stream) {
    const float* node_attr = (const float*)d_in[0];
    const float* edge_attr = (const float*)d_in[1];
    const int* edge_src = (const int*)d_in[2];
    const int* edge_dst = (const int*)d_in[3];
    const int* batch = (const int*)d_in[4];
    const float* Wl1 = (const float*)d_in[5];  const float* bl1 = (const float*)d_in[6];
    const float* Wr1 = (const float*)d_in[7];  const float* br1 = (const float*)d_in[8];
    const float* We1 = (const float*)d_in[9];  const float* att1 = (const float*)d_in[10];
    const float* b1 = (const float*)d_in[11];
    const float* Wl2 = (const float*)d_in[12]; const float* bl2 = (const float*)d_in[13];
    const float* Wr2 = (const float*)d_in[14]; const float* br2 = (const float*)d_in[15];
    const float* We2 = (const float*)d_in[16]; const float* att2 = (const float*)d_in[17];
    const float* b2 = (const float*)d_in[18];
    const float* Wd1 = (const float*)d_in[19]; const float* bd1 = (const float*)d_in[20];
    const float* bn_gamma = (const float*)d_in[21]; const float* bn_beta = (const float*)d_in[22];
    const float* bn_mean = (const float*)d_in[23];  const float* bn_var = (const float*)d_in[24];
    const float* Wd2 = (const float*)d_in[25]; const float* bd2 = (const float*)d_in[26];
    float* out = (float*)d_out;

    char* ws = (char*)d_ws;
    size_t off = 0;
    auto alloc = [&](size_t bytes) -> char* {
        char* p = ws + off;
        off = (off + bytes + 255) & ~(size_t)255;
        return p;
    };
    int* deg        = (int*)alloc((size_t)Nn * 4);
    int* row_start  = (int*)alloc((size_t)(Nn + 1) * 4);
    int* cursor     = (int*)alloc((size_t)Nn * 4);
    int* perm       = (int*)alloc((size_t)Ne * 4);
    float* pooled   = (float*)alloc((size_t)Gg * H2 * 4);
    float* cnt      = (float*)alloc((size_t)Gg * 4);
    float* xlb      = (float*)alloc((size_t)Nn * H1 * 4);
    float* xrb      = (float*)alloc((size_t)Nn * H1 * 4);
    float* x1       = (float*)alloc((size_t)Nn * H1 * 4);

    hipMemsetAsync(deg, 0, (size_t)Nn * 4, stream);
    hipMemsetAsync(cursor, 0, (size_t)Nn * 4, stream);
    hipMemsetAsync(pooled, 0, (size_t)Gg * H2 * 4, stream);
    hipMemsetAsync(cnt, 0, (size_t)Gg * 4, stream);

    count_deg_kernel<<<(Ne + 255) / 256, 256, 0, stream>>>(edge_dst, deg);
    scan_kernel<<<1, 1024, 0, stream>>>(deg, row_start);
    scatter_kernel<<<(Ne + 255) / 256, 256, 0, stream>>>(edge_dst, row_start, cursor, perm);

    // ---- layer 1: xl/xr GEMMs then fused GATv2 ----
    gemm_bias2_kernel<<<dim3(H1 / 64, (Nn + 63) / 64, 2), 256, 0, stream>>>(
        node_attr, Wl1, bl1, xlb, Wr1, br1, xrb, Nn, DIN, H1);
    fused_gat_kernel<H1><<<(Nn + 3) / 4, 256, 0, stream>>>(
        row_start, perm, edge_src, edge_attr, xlb, xrb, We1, att1, b1, x1);

    // ---- layer 2 ----
    gemm_bias2_kernel<<<dim3(H2 / 64, (Nn + 63) / 64, 2), 256, 0, stream>>>(
        x1, Wl2, bl2, xlb, Wr2, br2, xrb, Nn, H1, H2);
    float* x2 = x1;  // reuse
    fused_gat_kernel<H2><<<(Nn + 3) / 4, 256, 0, stream>>>(
        row_start, perm, edge_src, edge_attr, xlb, xrb, We2, att2, b2, x2);

    // ---- pool + head ----
    pool_kernel<<<(Nn * (H2 / 4) + 255) / 256, 256, 0, stream>>>(x2, batch, pooled, cnt);
    head_kernel<<<Gg, 64, 0, stream>>>(pooled, cnt, Wd1, bd1, bn_gamma, bn_beta,
                                       bn_mean, bn_var, Wd2, bd2, out);
}